// Round 6
// baseline (3448.288 us; speedup 1.0000x reference)
//
#include <hip/hip_runtime.h>
#include <hip/hip_fp16.h>
#include <stdint.h>

#define SEQ   1024
#define BATCH 128
#define INDIM 256
#define HID   512
#define INV_TAU 0.1f

typedef _Float16 f16;
typedef _Float16 f16x2 __attribute__((ext_vector_type(2)));
typedef _Float16 f16x8 __attribute__((ext_vector_type(8)));
typedef float    f32x4 __attribute__((ext_vector_type(4)));

static __device__ __forceinline__ f16x2 pk2(float a, float b) {
  auto r = __builtin_amdgcn_cvt_pkrtz(a, b);
  union { decltype(r) i; f16x2 o; } u;
  u.i = r;
  return u.o;
}

// ---------------------------------------------------------------------------
// K1: A = x @ win + bias  -> written into d_out (in place; K2 overwrites with h)
// ---------------------------------------------------------------------------
__global__ __launch_bounds__(512, 2)
void k1_gemm(const float* __restrict__ x, const float* __restrict__ win,
             const float* __restrict__ bias, float* __restrict__ out) {
  __shared__ __align__(16) f16x2 b_lds[HID][20];

  const int tid  = threadIdx.x;
  const int lane = tid & 63;
  const int wid  = tid >> 6;
  const int wr2  = wid >> 2;
  const int wc   = wid & 3;
  const int l15  = lane & 15;
  const int kg   = lane >> 4;

  const long m0 = (long)blockIdx.x * 64;

  f32x4 acc[2][8];
  #pragma unroll
  for (int a = 0; a < 2; ++a)
    #pragma unroll
    for (int bq = 0; bq < 8; ++bq) acc[a][bq] = (f32x4){0.f, 0.f, 0.f, 0.f};

  const int sp0 = (tid >> 8) * 8;
  const int sn0 = tid & 255;

  for (int ks = 0; ks < 8; ++ks) {
    const int k0 = ks * 32;
    #pragma unroll
    for (int r = 0; r < 8; ++r) {
      const int p = sp0 + r;
      #pragma unroll
      for (int i = 0; i < 2; ++i) {
        const int n = sn0 + 256 * i;
        const float lo = win[(k0 + 2 * p) * HID + n];
        const float hi = win[(k0 + 2 * p + 1) * HID + n];
        const int g  = p >> 2;
        const int gs = g ^ (n & 3);
        b_lds[n][gs * 4 + (p & 3)] = pk2(lo, hi);
      }
    }
    __syncthreads();

    f16x8 af[2];
    #pragma unroll
    for (int mf = 0; mf < 2; ++mf) {
      const long row = m0 + wr2 * 32 + mf * 16 + l15;
      const float4* xp = (const float4*)(x + row * INDIM + k0 + kg * 8);
      const float4 a0 = xp[0];
      const float4 a1 = xp[1];
      union { f16x2 h2[4]; f16x8 h8; } u;
      u.h2[0] = pk2(a0.x, a0.y); u.h2[1] = pk2(a0.z, a0.w);
      u.h2[2] = pk2(a1.x, a1.y); u.h2[3] = pk2(a1.z, a1.w);
      af[mf] = u.h8;
    }

    #pragma unroll
    for (int nf = 0; nf < 8; ++nf) {
      const int n  = wc * 128 + nf * 16 + l15;
      const int gs = kg ^ (n & 3);
      union { uint4 v; f16x8 h8; } u;
      u.v = *(const uint4*)&b_lds[n][gs * 4];
      #pragma unroll
      for (int mf = 0; mf < 2; ++mf)
        acc[mf][nf] = __builtin_amdgcn_mfma_f32_16x16x32_f16(af[mf], u.h8, acc[mf][nf], 0, 0, 0);
    }
    __syncthreads();
  }

  #pragma unroll
  for (int nf = 0; nf < 8; ++nf) {
    const int col = wc * 128 + nf * 16 + l15;
    const float bc = bias[col];
    #pragma unroll
    for (int mf = 0; mf < 2; ++mf) {
      const long rowb = m0 + wr2 * 32 + mf * 16 + kg * 4;
      #pragma unroll
      for (int r = 0; r < 4; ++r)
        out[(rowb + r) * HID + col] = acc[mf][nf][r] + bc;
    }
  }
}

// ---------------------------------------------------------------------------
// K2 (grid-split): 256 blocks x 512 threads, 1 block/CU, ALL CUs.
// Block = (row-pair rp = bid&63, col-chunk s = bid>>6): rows {2rp,2rp+1},
// cols [128s, 128s+128).
//
// ROUND-5 BUG FIX: the h stage is [2 bufs][2 rows][256 u32 k-pair words]
// = 1024 u32 = 4KB.  Round 5 allocated 2KB with row-stride 128 /
// buffer-stride 256 -> rows and buffers collided and buf1-row1 reads ran
// past the dynamic-LDS region (absmax 1.85e-02 + garbage in timing).
// Correct strides: row = 256 words, buffer = 512 words.  All mapping
// algebra re-verified: stage word for k-pair kp=(kso,io,jo) is
// r*256 + kso*32 + (io^kso)*4 + jo; reader at (ks,i,j) pulls word
// 32ks+4(i^ks)+j -> kp = 32ks+4i+j = weight slot kp.  Swizzle (i^ks)
// makes the 8 ks-octets of a wave hit 8 distinct 16B slots (conflict-free).
//
// DESIGN RULE (rounds 0-4): the compiler scratch-spills any large
// loop-invariant register mass (192/128/96 f16x2 all spilled).  So NOTHING
// persistent lives in registers except h/av.  Weights: 128KB LDS, streamed
// once per step (1024cy floor, lane-consecutive self-owned planes, zero
// conflicts -- proven round 4).  M=2 rows amortize the stream.
//
// h exchange per step: round-1-proven tagged mailbox, 4 peers.
// word = (t+1)<<16 | f16(h); relaxed AGENT atomics; slots double-buffered
// by (t+1)&1.  Publish strictly BEFORE spin.  Overwrite-before-read
// impossible: peer overwrites its tag-T word (with T+2) only at its step
// T+1, which needs my step-T publish, which is after my readers read tag T.
// ---------------------------------------------------------------------------
#define K2G_SMEM (131072 + 4096)
#define MBOX_WORDS (64 * 4 * 2 * 256)
#define MBOX_BYTES (MBOX_WORDS * 4)

__global__ __launch_bounds__(512)
void k2_grid(const float* __restrict__ wr, float* __restrict__ out,
             uint32_t* __restrict__ mbox) {
  extern __shared__ char smem[];
  uint4*    w4     = (uint4*)smem;                  // 16 planes x 512 = 128KB
  uint32_t* hstage = (uint32_t*)(smem + 131072);    // [2][2][256] u32 = 4KB

  const int tid = threadIdx.x;
  const int ks  = tid & 7;        // k-slice: k in [64ks, 64ks+64)
  const int cp  = tid >> 3;       // 0..63: local col pair {2cp, 2cp+1}
  const int bid = blockIdx.x;
  const int s   = bid >> 6;       // col-chunk 0..3
  const int rp  = bid & 63;       // row-pair
  const int c_even = 128 * s + 2 * cp;

  // ---- weights into LDS: plane p = c*8+i, slot w4[p*512+tid] holds k-pairs
  // kp = 32ks+4i..+3 of column c_even+c.  Self-owned -> loop reads are
  // lane-consecutive ds_read_b128, zero conflicts (proven round 4).
  #pragma unroll
  for (int c = 0; c < 2; ++c) {
    #pragma unroll
    for (int i = 0; i < 8; ++i) {
      union { uint4 v; f16x2 h2[4]; } u;
      #pragma unroll
      for (int j = 0; j < 4; ++j) {
        const int k = 64 * ks + 8 * i + 2 * j;
        u.h2[j] = pk2(wr[(long)k * HID + c_even + c],
                      wr[(long)(k + 1) * HID + c_even + c]);
      }
      w4[(c * 8 + i) * 512 + tid] = u.v;
    }
  }
  hstage[tid] = 0u; hstage[512 + tid] = 0u;   // both buffers, all 1024 words

  // ---- acting lanes (ks<4): own output (row = 2rp + (ks>>1), col parity ks&1)
  const bool act    = (ks < 4);
  const int  r_act  = ks >> 1;
  const int  cpar   = ks & 1;
  const int  col_local = 2 * cp + cpar;
  const int  col_act   = 128 * s + col_local;
  const long row_act   = 2 * rp + r_act;

  // own-stage u32 slot (even-parity acting lanes write the pair)
  const int kp_own = 64 * s + cp;
  const int kso = kp_own >> 5, io = (kp_own >> 2) & 7, jo = kp_own & 3;
  const int ownIdx = r_act * 256 + kso * 32 + ((io ^ kso) << 2) + jo;

  // ---- reader lanes (tid<384): one u32 stage-slot from one peer
  const bool rdr = (tid < 384);
  const int  pi  = tid >> 7;                          // 0..2
  const int  sp  = pi + (pi >= s ? 1 : 0);            // peer chunk id
  const int  w2  = (tid & 127) * 2;                   // mbox word idx (even)
  const int  r_p = (tid & 127) >> 6;
  const int  kpp = 64 * sp + ((w2 & 127) >> 1);
  const int  ksp = kpp >> 5, ip = (kpp >> 2) & 7, jp = kpp & 3;
  const int  rdIdx = r_p * 256 + ksp * 32 + ((ip ^ ksp) << 2) + jp;

  const long slot_me = ((long)(rp * 4 + s)) * 2;
  const long slot_pr = ((long)(rp * 4 + sp)) * 2;

  __syncthreads();

  float h  = 0.0f;
  float av = act ? out[row_act * HID + col_act] : 0.0f;   // A[0] prefetch

  const f16x2 Z2 = {(f16)0.f, (f16)0.f};
  const uint4* w4t = w4 + tid;

  #pragma unroll 1
  for (int t = 0; t < SEQ; ++t) {
    const int cur = t & 1;
    const int nxt = cur ^ 1;
    const uint4* hb = (const uint4*)(hstage + cur * 512);

    f16x2 a00 = Z2, a01 = Z2, a10 = Z2, a11 = Z2;
    #pragma unroll
    for (int i = 0; i < 8; ++i) {
      union { uint4 v; f16x2 h2[4]; } h0, h1, w0, w1;
      h0.v = hb[ks * 8 + (i ^ ks)];          // row 0: words 32ks+4(i^ks)+j
      h1.v = hb[64 + ks * 8 + (i ^ ks)];     // row 1: +256 words
      w0.v = w4t[i * 512];                   // col even
      w1.v = w4t[(8 + i) * 512];             // col odd
      #pragma unroll
      for (int j = 0; j < 4; ++j) {
        a00 = __builtin_elementwise_fma(h0.h2[j], w0.h2[j], a00);
        a01 = __builtin_elementwise_fma(h0.h2[j], w1.h2[j], a01);
        a10 = __builtin_elementwise_fma(h1.h2[j], w0.h2[j], a10);
        a11 = __builtin_elementwise_fma(h1.h2[j], w1.h2[j], a11);
      }
    }

    // reduce over the 8 ks-slices (octet butterfly, lane bits 0..2)
    float y00 = (float)a00[0] + (float)a00[1];
    float y01 = (float)a01[0] + (float)a01[1];
    float y10 = (float)a10[0] + (float)a10[1];
    float y11 = (float)a11[0] + (float)a11[1];
    y00 += __shfl_xor(y00, 1); y00 += __shfl_xor(y00, 2); y00 += __shfl_xor(y00, 4);
    y01 += __shfl_xor(y01, 1); y01 += __shfl_xor(y01, 2); y01 += __shfl_xor(y01, 4);
    y10 += __shfl_xor(y10, 1); y10 += __shfl_xor(y10, 2); y10 += __shfl_xor(y10, 4);
    y11 += __shfl_xor(y11, 1); y11 += __shfl_xor(y11, 2); y11 += __shfl_xor(y11, 4);

    int u16 = 0;
    if (act) {
      const float y   = (ks == 0) ? y00 : (ks == 1) ? y01 : (ks == 2) ? y10 : y11;
      const float arg = av + y;
      const float e   = __expf(2.0f * arg);
      const float th  = 1.0f - 2.0f / (e + 1.0f);
      h += INV_TAU * (th - h);

      const long aofs = ((long)t * BATCH + row_act) * HID + col_act;
      out[aofs] = h;
      union { f16 v; unsigned short u; } cv; cv.v = (f16)h; u16 = cv.u;
      if (t + 1 < SEQ) {
        // publish FIRST (peers spin on it) -- must precede any spin below
        __hip_atomic_store(mbox + (slot_me + nxt) * 256 + (r_act * 128 + col_local),
                           ((uint32_t)(t + 1) << 16) | (uint32_t)u16,
                           __ATOMIC_RELAXED, __HIP_MEMORY_SCOPE_AGENT);
        av = out[aofs + (long)BATCH * HID];   // A[t+1] prefetch (own slot, unwritten)
      }
    }

    // own-chunk staging: pair the two parities via shuffle (uniform exec)
    const int other = __shfl_xor(u16, 1);
    if (act && cpar == 0 && t + 1 < SEQ)
      hstage[nxt * 512 + ownIdx] = (uint32_t)(u16 & 0xffff) | ((uint32_t)other << 16);

    // peer staging: spin on self-validating tags, then one u32 LDS write
    if (rdr && t + 1 < SEQ) {
      const uint32_t want = (uint32_t)(t + 1);
      const uint32_t* p0 = mbox + (slot_pr + nxt) * 256 + w2;
      uint32_t v0 = __hip_atomic_load(p0, __ATOMIC_RELAXED, __HIP_MEMORY_SCOPE_AGENT);
      while ((v0 >> 16) != want) {
        __builtin_amdgcn_s_sleep(1);
        v0 = __hip_atomic_load(p0, __ATOMIC_RELAXED, __HIP_MEMORY_SCOPE_AGENT);
      }
      uint32_t v1 = __hip_atomic_load(p0 + 1, __ATOMIC_RELAXED, __HIP_MEMORY_SCOPE_AGENT);
      while ((v1 >> 16) != want) {
        __builtin_amdgcn_s_sleep(1);
        v1 = __hip_atomic_load(p0 + 1, __ATOMIC_RELAXED, __HIP_MEMORY_SCOPE_AGENT);
      }
      hstage[nxt * 512 + rdIdx] = (v0 & 0xffffu) | (v1 << 16);
    }
    __syncthreads();
  }
}

// ---------------------------------------------------------------------------
// K2 fallback (round-3 kernel) -- used only if the workspace is missing.
// ---------------------------------------------------------------------------
#define K2F_SMEM (131072 + 16384 + 2048)

#define DECL_W(u) f16x2 W##u##_0, W##u##_1, W##u##_2, W##u##_3;
#define INIT_U(u) { \
    _Pragma("unroll") \
    for (int r = 0; r < 8; ++r) { \
      const int k = (r >> 1) * 96 + 2 * (u) + (r & 1); \
      slab[r][tid] = wr[k * HID + tid]; \
    } \
    __syncthreads(); \
    W##u##_0 = pk2(slab[2*q][c4    ], slab[2*q+1][c4    ]); \
    W##u##_1 = pk2(slab[2*q][c4 + 1], slab[2*q+1][c4 + 1]); \
    W##u##_2 = pk2(slab[2*q][c4 + 2], slab[2*q+1][c4 + 2]); \
    W##u##_3 = pk2(slab[2*q][c4 + 3], slab[2*q+1][c4 + 3]); \
    __syncthreads(); }
#define FMA_U(u, i) { const f16x2 hh_##u = hu.h2[i]; \
    a0 = __builtin_elementwise_fma(hh_##u, W##u##_0, a0); \
    a1 = __builtin_elementwise_fma(hh_##u, W##u##_1, a1); \
    a2 = __builtin_elementwise_fma(hh_##u, W##u##_2, a2); \
    a3 = __builtin_elementwise_fma(hh_##u, W##u##_3, a3); }
#define GROUP(U, u0,u1,u2,u3) { \
    union { uint4 v; f16x2 h2[4]; } hu; \
    hu.v = *(const uint4*)&hb[q * 48 + (U) * 4]; \
    FMA_U(u0,0) FMA_U(u1,1) FMA_U(u2,2) FMA_U(u3,3) }

__global__ __launch_bounds__(512)
void k2_rnn(const float* __restrict__ wr, float* __restrict__ out) {
  extern __shared__ char smem[];
  uint4* w4          = (uint4*)smem;
  float (*slab)[HID] = (float(*)[HID])(smem + 131072);
  f16x2 (*hbuf)[256] = (f16x2(*)[256])(smem + 131072 + 16384);

  const int tid = threadIdx.x;
  const int q   = tid & 3;
  const int jj  = tid >> 2;
  const int c4  = jj * 4;
  const int b   = blockIdx.x;

  DECL_W(0)  DECL_W(1)  DECL_W(2)  DECL_W(3)  DECL_W(4)  DECL_W(5)
  DECL_W(6)  DECL_W(7)  DECL_W(8)  DECL_W(9)  DECL_W(10) DECL_W(11)
  DECL_W(12) DECL_W(13) DECL_W(14) DECL_W(15) DECL_W(16) DECL_W(17)
  DECL_W(18) DECL_W(19) DECL_W(20) DECL_W(21) DECL_W(22) DECL_W(23)
  DECL_W(24) DECL_W(25) DECL_W(26) DECL_W(27) DECL_W(28) DECL_W(29)
  DECL_W(30) DECL_W(31) DECL_W(32) DECL_W(33) DECL_W(34) DECL_W(35)
  DECL_W(36) DECL_W(37) DECL_W(38) DECL_W(39) DECL_W(40) DECL_W(41)
  DECL_W(42) DECL_W(43) DECL_W(44) DECL_W(45) DECL_W(46) DECL_W(47)

  #pragma unroll
  for (int gi = 0; gi < 4; ++gi) {
    #pragma unroll
    for (int m = 0; m < 4; ++m) {
      const int col = c4 + m;
      const int kb  = 384 + 32 * q + 8 * gi;
      union { uint4 v; f16x2 h2[4]; } u;
      #pragma unroll
      for (int i = 0; i < 4; ++i)
        u.h2[i] = pk2(wr[(long)(kb + 2 * i) * HID + col],
                      wr[(long)(kb + 2 * i + 1) * HID + col]);
      w4[(gi * 4 + m) * 512 + tid] = u.v;
    }
  }

  INIT_U(0)  INIT_U(1)  INIT_U(2)  INIT_U(3)  INIT_U(4)  INIT_U(5)
  INIT_U(6)  INIT_U(7)  INIT_U(8)  INIT_U(9)  INIT_U(10) INIT_U(11)
  INIT_U(12) INIT_U(13) INIT_U(14) INIT_U(15) INIT_U(16) INIT_U(17)
  INIT_U(18) INIT_U(19) INIT_U(20) INIT_U(21) INIT_U(22) INIT_U(23)
  INIT_U(24) INIT_U(25) INIT_U(26) INIT_U(27) INIT_U(28) INIT_U(29)
  INIT_U(30) INIT_U(31) INIT_U(32) INIT_U(33) INIT_U(34) INIT_U(35)
  INIT_U(36) INIT_U(37) INIT_U(38) INIT_U(39) INIT_U(40) INIT_U(41)
  INIT_U(42) INIT_U(43) INIT_U(44) INIT_U(45) INIT_U(46) INIT_U(47)

  const f16x2 Z2 = {(f16)0.f, (f16)0.f};
  if (tid < 256) { hbuf[0][tid] = Z2; hbuf[1][tid] = Z2; }
  __syncthreads();

  const int c = tid;
  float h = 0.0f;
  float av = out[(long)b * HID + c];
  const uint4* w4t = w4 + tid;

  #pragma unroll 1
  for (int t = 0; t < SEQ; ++t) {
    const int cur = t & 1;
    const int nxt = cur ^ 1;
    const long aofs = ((long)t * BATCH + b) * HID;
    const int tn = (t + 1 < SEQ) ? (t + 1) : (SEQ - 1);
    const float av_next = out[((long)tn * BATCH + b) * HID + c];

    const f16x2* hb = hbuf[cur];
    f16x2 a0 = Z2, a1 = Z2, a2 = Z2, a3 = Z2;

    GROUP(0,  0, 1, 2, 3)   GROUP(1,  4, 5, 6, 7)
    GROUP(2,  8, 9,10,11)   GROUP(3, 12,13,14,15)
    GROUP(4, 16,17,18,19)   GROUP(5, 20,21,22,23)
    GROUP(6, 24,25,26,27)   GROUP(7, 28,29,30,31)
    GROUP(8, 32,33,34,35)   GROUP(9, 36,37,38,39)
    GROUP(10,40,41,42,43)   GROUP(11,44,45,46,47)

    #pragma unroll
    for (int gi = 0; gi < 4; ++gi) {
      union { uint4 v; f16x2 h2[4]; } hu;
      hu.v = *(const uint4*)&hb[192 + q * 16 + gi * 4];
      union { uint4 v; f16x2 h2[4]; } w0, w1, w2, w3;
      w0.v = w4t[(gi * 4 + 0) * 512];
      w1.v = w4t[(gi * 4 + 1) * 512];
      w2.v = w4t[(gi * 4 + 2) * 512];
      w3.v = w4t[(gi * 4 + 3) * 512];
      #pragma unroll
      for (int i = 0; i < 4; ++i) {
        const f16x2 hh = hu.h2[i];
        a0 = __builtin_elementwise_fma(hh, w0.h2[i], a0);
        a1 = __builtin_elementwise_fma(hh, w1.h2[i], a1);
        a2 = __builtin_elementwise_fma(hh, w2.h2[i], a2);
        a3 = __builtin_elementwise_fma(hh, w3.h2[i], a3);
      }
    }

    float y0 = (float)a0[0] + (float)a0[1];
    float y1 = (float)a1[0] + (float)a1[1];
    float y2 = (float)a2[0] + (float)a2[1];
    float y3 = (float)a3[0] + (float)a3[1];
    y0 += __shfl_xor(y0, 1); y0 += __shfl_xor(y0, 2);
    y1 += __shfl_xor(y1, 1); y1 += __shfl_xor(y1, 2);
    y2 += __shfl_xor(y2, 1); y2 += __shfl_xor(y2, 2);
    y3 += __shfl_xor(y3, 1); y3 += __shfl_xor(y3, 2);
    const float y = (q == 0) ? y0 : (q == 1) ? y1 : (q == 2) ? y2 : y3;

    const float arg = av + y;
    const float e  = __expf(2.0f * arg);
    const float th = 1.0f - 2.0f / (e + 1.0f);
    h += INV_TAU * (th - h);

    out[aofs + c] = h;
    ((f16*)hbuf[nxt])[c] = (f16)h;
    av = av_next;
    __syncthreads();
  }
}

// ---------------------------------------------------------------------------
extern "C" void kernel_launch(void* const* d_in, const int* in_sizes, int n_in,
                              void* d_out, int out_size, void* d_ws, size_t ws_size,
                              hipStream_t stream) {
  const float* x    = (const float*)d_in[0];
  const float* win  = (const float*)d_in[1];
  const float* wr   = (const float*)d_in[2];
  const float* bias = (const float*)d_in[3];
  float* out = (float*)d_out;

  (void)in_sizes; (void)n_in; (void)out_size;

  k1_gemm<<<dim3((SEQ * BATCH) / 64), dim3(512), 0, stream>>>(x, win, bias, out);

  if (d_ws != nullptr && ws_size >= (size_t)MBOX_BYTES) {
    (void)hipFuncSetAttribute((const void*)k2_grid,
                              hipFuncAttributeMaxDynamicSharedMemorySize, K2G_SMEM);
    (void)hipMemsetAsync(d_ws, 0, MBOX_BYTES, stream);   // tags start at 0 each launch/replay
    k2_grid<<<dim3(256), dim3(512), K2G_SMEM, stream>>>(wr, out, (uint32_t*)d_ws);
  } else {
    (void)hipFuncSetAttribute((const void*)k2_rnn,
                              hipFuncAttributeMaxDynamicSharedMemorySize, K2F_SMEM);
    k2_rnn<<<dim3(BATCH), dim3(512), K2F_SMEM, stream>>>(wr, out);
  }
}

// Round 7
// 2805.204 us; speedup vs baseline: 1.2292x; 1.2292x over previous
//
#include <hip/hip_runtime.h>
#include <hip/hip_fp16.h>
#include <stdint.h>

#define SEQ   1024
#define BATCH 128
#define INDIM 256
#define HID   512
#define INV_TAU 0.1f

typedef _Float16 f16;
typedef _Float16 f16x2 __attribute__((ext_vector_type(2)));
typedef _Float16 f16x8 __attribute__((ext_vector_type(8)));
typedef float    f32x4 __attribute__((ext_vector_type(4)));

static __device__ __forceinline__ f16x2 pk2(float a, float b) {
  auto r = __builtin_amdgcn_cvt_pkrtz(a, b);
  union { decltype(r) i; f16x2 o; } u;
  u.i = r;
  return u.o;
}

static __device__ __forceinline__ uint32_t f2u(f16x2 x) {
  union { f16x2 h; uint32_t u; } c; c.h = x; return c.u;
}

// ---------------------------------------------------------------------------
// K1: A = x @ win + bias  -> written into d_out (in place; K2 overwrites with h)
// ---------------------------------------------------------------------------
__global__ __launch_bounds__(512, 2)
void k1_gemm(const float* __restrict__ x, const float* __restrict__ win,
             const float* __restrict__ bias, float* __restrict__ out) {
  __shared__ __align__(16) f16x2 b_lds[HID][20];

  const int tid  = threadIdx.x;
  const int lane = tid & 63;
  const int wid  = tid >> 6;
  const int wr2  = wid >> 2;
  const int wc   = wid & 3;
  const int l15  = lane & 15;
  const int kg   = lane >> 4;

  const long m0 = (long)blockIdx.x * 64;

  f32x4 acc[2][8];
  #pragma unroll
  for (int a = 0; a < 2; ++a)
    #pragma unroll
    for (int bq = 0; bq < 8; ++bq) acc[a][bq] = (f32x4){0.f, 0.f, 0.f, 0.f};

  const int sp0 = (tid >> 8) * 8;
  const int sn0 = tid & 255;

  for (int ks = 0; ks < 8; ++ks) {
    const int k0 = ks * 32;
    #pragma unroll
    for (int r = 0; r < 8; ++r) {
      const int p = sp0 + r;
      #pragma unroll
      for (int i = 0; i < 2; ++i) {
        const int n = sn0 + 256 * i;
        const float lo = win[(k0 + 2 * p) * HID + n];
        const float hi = win[(k0 + 2 * p + 1) * HID + n];
        const int g  = p >> 2;
        const int gs = g ^ (n & 3);
        b_lds[n][gs * 4 + (p & 3)] = pk2(lo, hi);
      }
    }
    __syncthreads();

    f16x8 af[2];
    #pragma unroll
    for (int mf = 0; mf < 2; ++mf) {
      const long row = m0 + wr2 * 32 + mf * 16 + l15;
      const float4* xp = (const float4*)(x + row * INDIM + k0 + kg * 8);
      const float4 a0 = xp[0];
      const float4 a1 = xp[1];
      union { f16x2 h2[4]; f16x8 h8; } u;
      u.h2[0] = pk2(a0.x, a0.y); u.h2[1] = pk2(a0.z, a0.w);
      u.h2[2] = pk2(a1.x, a1.y); u.h2[3] = pk2(a1.z, a1.w);
      af[mf] = u.h8;
    }

    #pragma unroll
    for (int nf = 0; nf < 8; ++nf) {
      const int n  = wc * 128 + nf * 16 + l15;
      const int gs = kg ^ (n & 3);
      union { uint4 v; f16x8 h8; } u;
      u.v = *(const uint4*)&b_lds[n][gs * 4];
      #pragma unroll
      for (int mf = 0; mf < 2; ++mf)
        acc[mf][nf] = __builtin_amdgcn_mfma_f32_16x16x32_f16(af[mf], u.h8, acc[mf][nf], 0, 0, 0);
    }
    __syncthreads();
  }

  #pragma unroll
  for (int nf = 0; nf < 8; ++nf) {
    const int col = wc * 128 + nf * 16 + l15;
    const float bc = bias[col];
    #pragma unroll
    for (int mf = 0; mf < 2; ++mf) {
      const long rowb = m0 + wr2 * 32 + mf * 16 + kg * 4;
      #pragma unroll
      for (int r = 0; r < 4; ++r)
        out[(rowb + r) * HID + col] = acc[mf][nf][r] + bc;
    }
  }
}

// ---------------------------------------------------------------------------
// K2: per-batch-row recurrence, 128 blocks x 512 threads, 1 block/CU.
//
// MODEL (rounds 0-6): 512-thread block => 2 waves/SIMD => HARD 256 total
// regs/wave.  The compiler splits 128 VGPR + 128 AGPR on its own and
// scratch-spills any weight mass beyond that; the per-step spill reloads
// (~390KB/CU/step from L2 at ~112B/cy) were the 3500cy/step stall behind
// every ~1750-1800us round.  Cross-CU exchange (rounds 1/6) costs 2-3us/step
// in agent-scope latency -- worse.  FIX: pin the weights in AGPRs OURSELVES.
//
// Per thread (q = tid&7 k-slice of 64 k, cols 8jj..8jj+7, owner col = tid):
//  - 23 k-pairs x 8 cols = 184 f16x2 in EXPLICIT AGPRs via inline asm
//    (v_accvgpr_write_b32 once at init; volatile v_accvgpr_read_b32 per use
//    so the reads can't be hoisted into 184 VGPR-resident copies -- the
//    exact mechanism that forced spills in rounds 0-4).
//    184 AGPR + <=72 VGPR = 256 total by construction: NO spill.
//  - 9 k-pairs in 147KB LDS: per-kp planes w4[plane*512+tid] (uint4 = 8
//    cols' f16x2), self-owned lane-consecutive ds_read_b128 (round-4
//    proven conflict-free).  Processed BEFORE the asm region so the loads
//    schedule freely.
//  - h broadcast in LDS, double-buffered, XOR-swizzled uint4 lines
//    phys = (W&56)|((W&7)^(W>>3)) so the 8 q-octets of a wave hit 8
//    distinct bank groups (conflict-free read & write).
//  - halving-butterfly octet reduce; all 512 lanes active; col = tid so
//    out-store / A-prefetch perfectly coalesced.  1 barrier/step.
// ---------------------------------------------------------------------------
#define K2_SMEM (147456 + 2048)

#define DECL_A(n) uint32_t A##n##_0, A##n##_1, A##n##_2, A##n##_3, \
                           A##n##_4, A##n##_5, A##n##_6, A##n##_7;

#define WRA(d, s) asm volatile("v_accvgpr_write_b32 %0, %1" : "=a"(d) : "v"(s));

#define INIT_A(n) { \
  const float* r0_ = wq + (long)(2 * (n)) * HID; \
  const float* r1_ = r0_ + HID; \
  const float2 xa_ = *(const float2*)(r0_    ), ya_ = *(const float2*)(r1_    ); \
  const float2 xb_ = *(const float2*)(r0_ + 2), yb_ = *(const float2*)(r1_ + 2); \
  const float2 xc_ = *(const float2*)(r0_ + 4), yc_ = *(const float2*)(r1_ + 4); \
  const float2 xd_ = *(const float2*)(r0_ + 6), yd_ = *(const float2*)(r1_ + 6); \
  WRA(A##n##_0, f2u(pk2(xa_.x, ya_.x)))  WRA(A##n##_1, f2u(pk2(xa_.y, ya_.y))) \
  WRA(A##n##_2, f2u(pk2(xb_.x, yb_.x)))  WRA(A##n##_3, f2u(pk2(xb_.y, yb_.y))) \
  WRA(A##n##_4, f2u(pk2(xc_.x, yc_.x)))  WRA(A##n##_5, f2u(pk2(xc_.y, yc_.y))) \
  WRA(A##n##_6, f2u(pk2(xd_.x, yd_.x)))  WRA(A##n##_7, f2u(pk2(xd_.y, yd_.y))) }

#define FMA1(n, m) { uint32_t t_; \
  asm volatile("v_accvgpr_read_b32 %0, %1" : "=v"(t_) : "a"(A##n##_##m)); \
  union { uint32_t u; f16x2 h; } c_; c_.u = t_; \
  a##m = __builtin_elementwise_fma(hh_, c_.h, a##m); }

#define FMA_A(n) { const f16x2 hh_ = hu[(n) >> 2].h2[(n) & 3]; \
  FMA1(n,0) FMA1(n,1) FMA1(n,2) FMA1(n,3) FMA1(n,4) FMA1(n,5) FMA1(n,6) FMA1(n,7) }

#define FMA_L(n) { const f16x2 hh_ = hu[(n) >> 2].h2[(n) & 3]; \
  union { uint4 v; f16x2 h2[4]; } w0_, w1_; \
  w0_.v = w4t[(2 * ((n) - 23)    ) * 512]; \
  w1_.v = w4t[(2 * ((n) - 23) + 1) * 512]; \
  a0 = __builtin_elementwise_fma(hh_, w0_.h2[0], a0); \
  a1 = __builtin_elementwise_fma(hh_, w0_.h2[1], a1); \
  a2 = __builtin_elementwise_fma(hh_, w0_.h2[2], a2); \
  a3 = __builtin_elementwise_fma(hh_, w0_.h2[3], a3); \
  a4 = __builtin_elementwise_fma(hh_, w1_.h2[0], a4); \
  a5 = __builtin_elementwise_fma(hh_, w1_.h2[1], a5); \
  a6 = __builtin_elementwise_fma(hh_, w1_.h2[2], a6); \
  a7 = __builtin_elementwise_fma(hh_, w1_.h2[3], a7); }

__global__ __launch_bounds__(512)
void k2_rnn(const float* __restrict__ wr, float* __restrict__ out) {
  extern __shared__ char smem[];
  uint4*    w4  = (uint4*)smem;                    // 18 planes x 512 x 16B = 144KB
  uint32_t* hbs = (uint32_t*)(smem + 147456);      // [2][256] u32 = 2KB (h, f16)

  const int tid = threadIdx.x;
  const int q   = tid & 7;        // k-slice: k in [64q, 64q+64)  (kp 32q..32q+31)
  const int jj  = tid >> 3;       // cols 8jj .. 8jj+7
  const int b   = blockIdx.x;

  const float* wq = wr + (long)(64 * q) * HID + 8 * jj;

  DECL_A(0)  DECL_A(1)  DECL_A(2)  DECL_A(3)  DECL_A(4)  DECL_A(5)
  DECL_A(6)  DECL_A(7)  DECL_A(8)  DECL_A(9)  DECL_A(10) DECL_A(11)
  DECL_A(12) DECL_A(13) DECL_A(14) DECL_A(15) DECL_A(16) DECL_A(17)
  DECL_A(18) DECL_A(19) DECL_A(20) DECL_A(21) DECL_A(22)

  INIT_A(0)  INIT_A(1)  INIT_A(2)  INIT_A(3)  INIT_A(4)  INIT_A(5)
  INIT_A(6)  INIT_A(7)  INIT_A(8)  INIT_A(9)  INIT_A(10) INIT_A(11)
  INIT_A(12) INIT_A(13) INIT_A(14) INIT_A(15) INIT_A(16) INIT_A(17)
  INIT_A(18) INIT_A(19) INIT_A(20) INIT_A(21) INIT_A(22)

  // ---- LDS weight planes: kp_local n in [23,32), plane pair (2(n-23)+cc)
  #pragma unroll
  for (int n = 23; n < 32; ++n) {
    const float* r0 = wq + (long)(2 * n) * HID;
    const float* r1 = r0 + HID;
    #pragma unroll
    for (int cc = 0; cc < 2; ++cc) {
      union { uint4 v; f16x2 h2[4]; } u;
      #pragma unroll
      for (int m = 0; m < 4; ++m)
        u.h2[m] = pk2(r0[4 * cc + m], r1[4 * cc + m]);
      w4[(2 * (n - 23) + cc) * 512 + tid] = u.v;
    }
  }

  hbs[tid] = 0u;          // zero both h buffers (512 u32)
  __syncthreads();

  // swizzled write slot for h[col=tid]: logical uint4 W=tid>>3,
  // phys = (W&56) | ((W&7)^(W>>3)); f16 slot = phys*8 + (tid&7)
  const int Wn    = tid >> 3;
  const int physW = (Wn & 56) | ((Wn & 7) ^ (Wn >> 3));
  const int hpos  = physW * 8 + (tid & 7);

  const uint4* w4t = w4 + tid;

  float h  = 0.0f;
  float av = out[(long)b * HID + tid];   // A[0] prefetch (col = tid, coalesced)

  const f16x2 Z2 = {(f16)0.f, (f16)0.f};

  #pragma unroll 1
  for (int t = 0; t < SEQ; ++t) {
    const int cur = t & 1;
    const int nxt = cur ^ 1;
    const long aofs = ((long)t * BATCH + b) * HID;
    const int  tn   = (t + 1 < SEQ) ? (t + 1) : (SEQ - 1);
    const float av_next = out[((long)tn * BATCH + b) * HID + tid];

    const uint4* hb4 = ((const uint4*)hbs) + cur * 64;

    // h broadcast reads: logical W = 8q+w at phys 8q + (w^q) -> 8 distinct
    // bank groups per wave (conflict-free)
    union HU { uint4 v; f16x2 h2[4]; } hu[8];
    #pragma unroll
    for (int w = 0; w < 8; ++w)
      hu[w].v = hb4[8 * q + (w ^ q)];

    f16x2 a0 = Z2, a1 = Z2, a2 = Z2, a3 = Z2,
          a4 = Z2, a5 = Z2, a6 = Z2, a7 = Z2;

    // LDS-weight kps first (ds_reads schedule freely, before the asm region)
    FMA_L(23) FMA_L(24) FMA_L(25) FMA_L(26) FMA_L(27)
    FMA_L(28) FMA_L(29) FMA_L(30) FMA_L(31)

    // AGPR-weight kps: 184 volatile accvgpr_read + pk_fma, zero memory traffic
    FMA_A(0)  FMA_A(1)  FMA_A(2)  FMA_A(3)  FMA_A(4)  FMA_A(5)
    FMA_A(6)  FMA_A(7)  FMA_A(8)  FMA_A(9)  FMA_A(10) FMA_A(11)
    FMA_A(12) FMA_A(13) FMA_A(14) FMA_A(15) FMA_A(16) FMA_A(17)
    FMA_A(18) FMA_A(19) FMA_A(20) FMA_A(21) FMA_A(22)

    // halving-butterfly reduce across the q-octet (lane bits 0..2)
    float y0 = (float)a0[0] + (float)a0[1];
    float y1 = (float)a1[0] + (float)a1[1];
    float y2 = (float)a2[0] + (float)a2[1];
    float y3 = (float)a3[0] + (float)a3[1];
    float y4 = (float)a4[0] + (float)a4[1];
    float y5 = (float)a5[0] + (float)a5[1];
    float y6 = (float)a6[0] + (float)a6[1];
    float y7 = (float)a7[0] + (float)a7[1];

    const float z0 = ((q & 4) ? y4 : y0) + __shfl_xor((q & 4) ? y0 : y4, 4);
    const float z1 = ((q & 4) ? y5 : y1) + __shfl_xor((q & 4) ? y1 : y5, 4);
    const float z2 = ((q & 4) ? y6 : y2) + __shfl_xor((q & 4) ? y2 : y6, 4);
    const float z3 = ((q & 4) ? y7 : y3) + __shfl_xor((q & 4) ? y3 : y7, 4);
    const float u0 = ((q & 2) ? z2 : z0) + __shfl_xor((q & 2) ? z0 : z2, 2);
    const float u1 = ((q & 2) ? z3 : z1) + __shfl_xor((q & 2) ? z1 : z3, 2);
    const float y  = ((q & 1) ? u1 : u0) + __shfl_xor((q & 1) ? u0 : u1, 1);
    // y = dot(h, wr[:, col]) for col = 8jj + q = tid

    // leaky update: h += 0.1*(tanh(A + y) - h)
    const float arg = av + y;
    const float e  = __expf(2.0f * arg);
    const float th = 1.0f - 2.0f / (e + 1.0f);
    h += INV_TAU * (th - h);

    out[aofs + tid] = h;                          // coalesced
    ((f16*)(hbs + nxt * 256))[hpos] = (f16)h;     // swizzled, conflict-free
    av = av_next;
    __syncthreads();
  }
}

// ---------------------------------------------------------------------------
extern "C" void kernel_launch(void* const* d_in, const int* in_sizes, int n_in,
                              void* d_out, int out_size, void* d_ws, size_t ws_size,
                              hipStream_t stream) {
  const float* x    = (const float*)d_in[0];
  const float* win  = (const float*)d_in[1];
  const float* wr   = (const float*)d_in[2];
  const float* bias = (const float*)d_in[3];
  float* out = (float*)d_out;

  (void)d_ws; (void)ws_size; (void)in_sizes; (void)n_in; (void)out_size;

  (void)hipFuncSetAttribute((const void*)k2_rnn,
                            hipFuncAttributeMaxDynamicSharedMemorySize, K2_SMEM);

  k1_gemm<<<dim3((SEQ * BATCH) / 64), dim3(512), 0, stream>>>(x, win, bias, out);
  k2_rnn<<<dim3(BATCH), dim3(512), K2_SMEM, stream>>>(wr, out);
}